// Round 7
// baseline (1204.649 us; speedup 1.0000x reference)
//
#include <hip/hip_runtime.h>

// ============================================================================
// CharLevelEncoder R12: 2 blocks/CU at constant thread-steps + work queue.
// Surviving facts after R5-R11:
//  (1) Mystery HBM traffic = ~62 B/thread-step each way, proportional to
//      THREADS (R9 512thr:137MB -> R10 1024thr:278MB), invariant to register
//      config. Can't remove it; don't multiply it (R10's mistake).
//  (2) Best config (R7, 299us) is stall-bound: 42K cyc/CU-step vs <=15K
//      modeled pipe work at Occupancy 22% -- capped by grid=256 (1 block/CU)
//      + waves_per_eu(2,2).
// R12: R7's exact 512-thr/36KB-LDS/128-VGPR block, but 512 blocks (2/CU:
// 2 x 8 waves x 128 regs = 2048 = full pool, 72KB <= 160KB LDS), ONE slice
// per block -> total thread-steps unchanged. Placement-robust balance via
// persistent atomic queue, longest-first (LPT). waves_per_eu(4,4) caps
// alloc at 128 so 2 blocks co-reside.
// Cleanups: wemb loads lose NT (4x wave reuse -> let L2 serve); launches
// merged 7 -> 4 (prep0|hist|prep2, scan|prep1, scatter, main).
// ============================================================================

#define NW 32768

typedef __attribute__((ext_vector_type(8))) short short8;
typedef __attribute__((ext_vector_type(4))) float f32x4;
typedef __attribute__((ext_vector_type(4))) int i32x4;
typedef __attribute__((ext_vector_type(4))) unsigned short u16x4;

#define MFMA16(a,b,c) __builtin_amdgcn_mfma_f32_16x16x32_bf16(a,b,c,0,0,0)
#define MFMAI8(a,b,c) __builtin_amdgcn_mfma_i32_16x16x32_i8(a,b,c,0,0,0)

// ---- workspace layout (bytes) ----
#define O_ORDER 0           // i32[32768] sorted word ids (asc len)
#define O_SLEN  131072      // i32[32768] sorted lengths
#define O_WPK   262144      // i8 packed W_hh' fragments (262144)
#define O_USTP  524288      // f32[1024] u' = rowmax(whh)/(127*127)
#define O_WLIN  528384      // bf16 packed W_lin fragments (262144)
#define O_PX    790528      // bf16[256][256][4] x-proj+bias table (524288)
#define O_BH    1314816     // i32[128][16] per-block length histograms
#define O_BASE  1323008     // i32[128][16] scatter bases
#define O_CTR   1331200     // i32 persistent work-queue counter
// total 1331204 B

__device__ inline unsigned short f2b(float f) {   // fp32 -> bf16 RNE
  unsigned u = __builtin_bit_cast(unsigned, f);
  u = u + 0x7fffu + ((u >> 16) & 1u);
  return (unsigned short)(u >> 16);
}
__device__ inline float b2f(unsigned short u) {
  return __builtin_bit_cast(float, ((unsigned)u) << 16);
}
__device__ inline float fsigm(float x) {
  float e = __builtin_amdgcn_exp2f(-1.44269504f * x);
  return __builtin_amdgcn_rcpf(1.0f + e);
}
__device__ inline float ftanh(float x) {
  float e = __builtin_amdgcn_exp2f(2.88539008f * x);
  return 1.0f - 2.0f * __builtin_amdgcn_rcpf(e + 1.0f);
}

// ---- prepA: prep0 (row scales) | hist | prep2 (PX table) | ctr=0 ----
__global__ void k_prepA(const float* __restrict__ whh, const int* __restrict__ lens,
                        const float* __restrict__ wih, const float* __restrict__ ech,
                        const float* __restrict__ bih, const float* __restrict__ bhh,
                        unsigned char* __restrict__ ws) {
  int bid = blockIdx.x, tid = threadIdx.x;
  if (bid == 0 && tid == 0) *(int*)(ws + O_CTR) = 0;
  if (bid < 4) {                        // prep0: per-row scales over W_hh
    int i = bid * 256 + tid;            // 0..1023
    const f32x4* r4 = (const f32x4*)(whh + i * 256);
    float mx = 0.f;
    #pragma unroll 8
    for (int k4 = 0; k4 < 64; ++k4) {
      f32x4 v = r4[k4];
      mx = fmaxf(mx, fmaxf(fmaxf(fabsf(v[0]), fabsf(v[1])),
                           fmaxf(fabsf(v[2]), fabsf(v[3]))));
    }
    ((float*)(ws + O_USTP))[i] = mx / (127.f * 127.f);
    return;
  }
  if (bid < 132) {                      // hist (128 blocks)
    __shared__ int h[16];
    int b2 = bid - 4;
    if (tid < 16) h[tid] = 0;
    __syncthreads();
    int wid = b2 * 256 + tid;
    int l = lens[wid]; l = l < 1 ? 1 : (l > 16 ? 16 : l);
    atomicAdd(&h[l - 1], 1);
    __syncthreads();
    if (tid < 16) ((int*)(ws + O_BH))[b2 * 16 + tid] = h[tid];
    return;
  }
  // prep2: PX[c][hd][g] (1024 blocks)
  int id = (bid - 132) * 256 + tid;     // 0..262143
  int c = id >> 10, n = id & 1023;
  const f32x4* w4 = (const f32x4*)(wih + n * 64);
  const f32x4* e4 = (const f32x4*)(ech + c * 64);
  float acc = bih[n] + bhh[n];
  #pragma unroll
  for (int k4 = 0; k4 < 16; ++k4) {
    f32x4 a = w4[k4], e = e4[k4];
    acc += a[0] * e[0] + a[1] * e[1] + a[2] * e[2] + a[3] * e[3];
  }
  ((unsigned short*)(ws + O_PX))[((c << 8) + (n & 255)) * 4 + (n >> 8)] = f2b(acc);
}

// ---- prepB: scan (block 0) | prep1 pack W_hh' + W_lin (blocks 1..1536) ----
__global__ void k_prepB(const float* __restrict__ whh, const float* __restrict__ wlin,
                        unsigned char* __restrict__ ws) {
  int bid = blockIdx.x, tid = threadIdx.x;
  if (bid == 0) {                       // scan of 128x16 histograms
    __shared__ int tot[16], g[16];
    const int* bh = (const int*)(ws + O_BH);
    int* base = (int*)(ws + O_BASE);
    if (tid < 16) {
      int s = 0;
      for (int b = 0; b < 128; ++b) s += bh[b * 16 + tid];
      tot[tid] = s;
    }
    __syncthreads();
    if (tid == 0) { int a = 0; for (int i = 0; i < 16; ++i) { g[i] = a; a += tot[i]; } }
    __syncthreads();
    if (tid < 16) {
      int run = g[tid];
      for (int b = 0; b < 128; ++b) { base[b * 16 + tid] = run; run += bh[b * 16 + tid]; }
    }
    return;
  }
  int i = (bid - 1) * 256 + tid;        // 0..393215
  if (i < 262144) {                     // W_hh' i8 fragment pack
    int j = i & 7, lane = (i >> 3) & 63, t2 = i >> 9;
    int nt = t2 & 7, u2 = t2 >> 3;
    int kb = u2 & 7, w = u2 >> 3;
    int n = (nt >> 1) * 256 + w * 32 + (nt & 1) * 16 + (lane & 15);
    int k = kb * 32 + (lane >> 4) * 8 + j;
    float v = whh[n * 256 + k];
    float ustep = ((const float*)(ws + O_USTP))[n] * 127.f;   // rowmax/127
    float qf = (ustep > 0.f) ? v / ustep : 0.f;
    int q = (int)__builtin_rintf(qf);
    q = q < -127 ? -127 : (q > 127 ? 127 : q);
    ((signed char*)(ws + O_WPK))[i] = (signed char)q;
    return;
  }
  int i2 = i - 262144;                  // < 131072, W_lin bf16 pack
  {
    int j = i2 & 7, lane = (i2 >> 3) & 63, t3 = i2 >> 9;
    int kf = t3 & 15, nn = t3 >> 4;
    int n = (nn >> 2) * 64 + (nn & 3) * 16 + (lane & 15);
    int k = kf * 32 + (lane >> 4) * 8 + j;
    ((unsigned short*)(ws + O_WLIN))[i2] = f2b(wlin[n * 512 + k]);
  }
}

// ---- scatter (needs BASE) ----
__global__ void k_scatter(const int* __restrict__ lens, unsigned char* __restrict__ ws) {
  __shared__ int cnt[16];
  int t = threadIdx.x, b = blockIdx.x;
  if (t < 16) cnt[t] = 0;
  __syncthreads();
  int wid = b * 256 + t;
  int l = lens[wid]; l = l < 1 ? 1 : (l > 16 ? 16 : l);
  int rank = atomicAdd(&cnt[l - 1], 1);
  int p = ((const int*)(ws + O_BASE))[b * 16 + (l - 1)] + rank;
  ((int*)(ws + O_ORDER))[p] = wid;
  ((int*)(ws + O_SLEN))[p] = l;
}

// ---- main persistent kernel: 512 blocks x 512 threads, 2 blocks/CU ----
__global__ __launch_bounds__(512)
__attribute__((amdgpu_waves_per_eu(4, 4)))
void k_main(
    const int* __restrict__ cidx, const float* __restrict__ wemb,
    const float* __restrict__ blin, float* __restrict__ outp,
    unsigned char* __restrict__ ws) {
  // Xb: double-buffered h-state, i8. [buf][mt][kb][lane][8]
  __shared__ signed char Xb[2][4][8][64][8];   // 32 KB
  __shared__ int CW[64][16];                   //  4 KB
  __shared__ int s_slice;

  const int tid = threadIdx.x;
  const int w = tid >> 6, lane = tid & 63;
  const int q = lane >> 4, l15 = lane & 15;

  const int* order = (const int*)(ws + O_ORDER);
  const int* slen  = (const int*)(ws + O_SLEN);
  const signed char* wpk = (const signed char*)(ws + O_WPK);
  const float* upt = (const float*)(ws + O_USTP);
  const unsigned short* wlin = (const unsigned short*)(ws + O_WLIN);
  const unsigned short* pxt = (const unsigned short*)(ws + O_PX);

  // ---- prologue: all of W_hh' -> VGPRs (128 regs), scales ----
  long wreg[8][8];
  #pragma unroll
  for (int kb = 0; kb < 8; ++kb)
    #pragma unroll
    for (int nt = 0; nt < 8; ++nt)
      wreg[kb][nt] = *(const long*)(wpk + (((w * 8 + kb) * 8 + nt) * 64 + lane) * 8);

  float uq[8];
  #pragma unroll
  for (int nt = 0; nt < 8; ++nt) {
    int n = (nt >> 1) * 256 + w * 32 + (nt & 1) * 16 + l15;
    uq[nt] = upt[n];
  }
  const int hd0 = w * 32 + l15;          // hdim at hs=0 (hs adds +16)
  const int mh = w >> 2, nw = w & 3;
  float blv[4];
  #pragma unroll
  for (int nt = 0; nt < 4; ++nt) blv[nt] = blin[nw * 64 + nt * 16 + l15];

  // ---- persistent work queue: grab slices, longest-first (LPT) ----
  for (;;) {
    if (tid == 0) s_slice = atomicAdd((int*)(ws + O_CTR), 1);
    __syncthreads();                    // s_slice visible; prev epilogue done
    const int p = s_slice;
    if (p >= 512) break;
    const int s = 511 - p;              // longest slices first
    const int base = 64 * s;

    { // zero Xb buf0 h-state (16 KB)
      long* pz = (long*)&Xb[0][0][0][0][0];
      #pragma unroll
      for (int ii = 0; ii < 4; ++ii) pz[tid + 512 * ii] = 0L;
    }
    if (tid < 256) {                    // this slice's char indices (streamed once)
      int m = tid >> 2, part = tid & 3;
      int wid = order[base + m];
      *(i32x4*)&CW[m][part * 4] =
          __builtin_nontemporal_load((const i32x4*)(cidx + wid * 16 + part * 4));
    }
    int tmax[4]; unsigned lenpk[4];
    #pragma unroll
    for (int mt = 0; mt < 4; ++mt) {
      int pbm = base + 16 * mt;
      tmax[mt] = slen[pbm + 15];
      unsigned l0 = (unsigned)slen[pbm + q * 4 + 0];
      unsigned l1 = (unsigned)slen[pbm + q * 4 + 1];
      unsigned l2 = (unsigned)slen[pbm + q * 4 + 2];
      unsigned l3 = (unsigned)slen[pbm + q * 4 + 3];
      lenpk[mt] = l0 | (l1 << 8) | (l2 << 16) | (l3 << 24);
    }
    const int Tm = tmax[3];
    __syncthreads();                    // CW + zeroing visible

    float creg[4][2][4];
    unsigned hreg[4][2];
    #pragma unroll
    for (int mt = 0; mt < 4; ++mt)
      #pragma unroll
      for (int hs = 0; hs < 2; ++hs) {
        hreg[mt][hs] = 0u;
        #pragma unroll
        for (int r = 0; r < 4; ++r) creg[mt][hs][r] = 0.f;
      }

    for (int t = 0; t < Tm; ++t) {
      const int rd = t & 1, wb = rd ^ 1;
      #pragma unroll
      for (int mt = 0; mt < 4; ++mt) {
        if (mt != 3 && t >= tmax[mt]) continue;   // wave-uniform
        int cc[4];
        #pragma unroll
        for (int r = 0; r < 4; ++r) cc[r] = CW[mt * 16 + q * 4 + r][t] & 255;
        #pragma unroll
        for (int hs = 0; hs < 2; ++hs) {
          u16x4 pb[4];
          #pragma unroll
          for (int r = 0; r < 4; ++r)
            pb[r] = *(const u16x4*)&pxt[((cc[r] << 8) + hd0 + hs * 16) * 4];
          i32x4 a0 = (i32x4)0, a1 = (i32x4)0, a2 = (i32x4)0, a3 = (i32x4)0;
          #pragma unroll
          for (int kb = 0; kb < 8; ++kb) {
            long A = *(const long*)&Xb[rd][mt][kb][lane][0];
            a0 = MFMAI8(A, wreg[kb][0 + hs], a0);
            a1 = MFMAI8(A, wreg[kb][2 + hs], a1);
            a2 = MFMAI8(A, wreg[kb][4 + hs], a2);
            a3 = MFMAI8(A, wreg[kb][6 + hs], a3);
          }
          // gates + LSTM update; C-layout row(word) = q*4+r, col(n) = l15
          unsigned hp = 0;
          #pragma unroll
          for (int r = 0; r < 4; ++r) {
            float gi = (float)a0[r] * uq[0 + hs] + b2f(pb[r][0]);
            float gf = (float)a1[r] * uq[2 + hs] + b2f(pb[r][1]);
            float gg = (float)a2[r] * uq[4 + hs] + b2f(pb[r][2]);
            float go = (float)a3[r] * uq[6 + hs] + b2f(pb[r][3]);
            float si = fsigm(gi), sf = fsigm(gf);
            float sg = ftanh(gg), so = fsigm(go);
            float cold = creg[mt][hs][r];
            float cn = sf * cold + si * sg;
            float hn = so * ftanh(cn);
            int lene = (int)((lenpk[mt] >> (8 * r)) & 255u);
            bool live = t < lene;
            creg[mt][hs][r] = live ? cn : cold;
            int hq = (int)__builtin_rintf(127.f * hn);   // |hn|<1 -> no clamp
            unsigned ob = (hreg[mt][hs] >> (8 * r)) & 255u;
            unsigned nb = live ? ((unsigned)hq & 255u) : ob;
            hp |= nb << (8 * r);
          }
          hreg[mt][hs] = hp;
        }
      } // mt

      // h write-back into the OTHER buffer (always-write; wave w owns kb = w)
      #pragma unroll
      for (int mt = 0; mt < 4; ++mt) {
        if (mt != 3 && t >= tmax[mt]) continue;
        #pragma unroll
        for (int hs = 0; hs < 2; ++hs) {
          int row16 = 16 * (hs * 2 + (l15 >> 3));
          #pragma unroll
          for (int r = 0; r < 4; ++r)
            Xb[wb][mt][w][(q * 4 + r) + row16][l15 & 7] =
                (signed char)((hreg[mt][hs] >> (8 * r)) & 255u);
        }
      }
      __syncthreads();                  // single barrier per step
    } // t

    // ---- fused final linear for this slice (bf16 MFMA) ----
    int widA[2];
    #pragma unroll
    for (int mi = 0; mi < 2; ++mi) widA[mi] = order[base + (2 * mh + mi) * 16 + l15];
    const int tb0 = (mh ? tmax[2] : tmax[0]) & 1;   // buffer holding final h
    const int tb1 = (mh ? tmax[3] : tmax[1]) & 1;
    f32x4 fac[2][4];
    #pragma unroll
    for (int mi = 0; mi < 2; ++mi)
      #pragma unroll
      for (int nt = 0; nt < 4; ++nt) fac[mi][nt] = 0.0f;

    #pragma unroll
    for (int kf = 0; kf < 16; ++kf) {
      short8 Bn[4];
      #pragma unroll
      for (int nt = 0; nt < 4; ++nt)
        Bn[nt] = ((const short8*)wlin)[((nw * 4 + nt) * 16 + kf) * 64 + lane];
      short8 Am[2];
      #pragma unroll
      for (int mi = 0; mi < 2; ++mi) {
        if (kf < 8) {                   // word_emb fp32 -> bf16 (L2 reuse x4: no NT)
          const f32x4* pa = (const f32x4*)(wemb + widA[mi] * 256 + kf * 32 + q * 8);
          f32x4 f0 = pa[0];
          f32x4 f1 = pa[1];
          short8 A;
          A[0] = (short)f2b(f0[0]); A[1] = (short)f2b(f0[1]);
          A[2] = (short)f2b(f0[2]); A[3] = (short)f2b(f0[3]);
          A[4] = (short)f2b(f1[0]); A[5] = (short)f2b(f1[1]);
          A[6] = (short)f2b(f1[2]); A[7] = (short)f2b(f1[3]);
          Am[mi] = A;
        } else {                        // final h from Xb i8 -> bf16
          int mtv = 2 * mh + mi;
          int tb = mi ? tb1 : tb0;
          long ch = *(const long*)&Xb[tb][mtv][kf - 8][lane][0];
          short8 A;
          #pragma unroll
          for (int j = 0; j < 8; ++j) {
            int v = (int)(signed char)((ch >> (8 * j)) & 255);
            A[j] = (short)f2b((float)v * (1.f / 127.f));
          }
          Am[mi] = A;
        }
      }
      #pragma unroll
      for (int mi = 0; mi < 2; ++mi)
        #pragma unroll
        for (int nt = 0; nt < 4; ++nt)
          fac[mi][nt] = MFMA16(Am[mi], Bn[nt], fac[mi][nt]);
    }
    #pragma unroll
    for (int mi = 0; mi < 2; ++mi) {
      #pragma unroll
      for (int r = 0; r < 4; ++r) {
        int wid = order[base + (2 * mh + mi) * 16 + q * 4 + r];
        float* po = outp + wid * 256 + nw * 64 + l15;
        #pragma unroll
        for (int nt = 0; nt < 4; ++nt) {
          float v = fac[mi][nt][r] + blv[nt];
          __builtin_nontemporal_store(v > 0.f ? v : 0.f, po + nt * 16);
        }
      }
    }
  } // queue
}

extern "C" void kernel_launch(void* const* d_in, const int* in_sizes, int n_in,
                              void* d_out, int out_size, void* d_ws, size_t ws_size,
                              hipStream_t stream) {
  const int*   cidx = (const int*)d_in[0];
  const int*   clen = (const int*)d_in[1];
  const float* wemb = (const float*)d_in[2];
  const float* ech  = (const float*)d_in[3];
  const float* wih  = (const float*)d_in[4];
  const float* whh  = (const float*)d_in[5];
  const float* bih  = (const float*)d_in[6];
  const float* bhh  = (const float*)d_in[7];
  const float* wlin = (const float*)d_in[8];
  const float* blin = (const float*)d_in[9];
  float* outp = (float*)d_out;
  unsigned char* ws = (unsigned char*)d_ws;

  k_prepA<<<1156, 256, 0, stream>>>(whh, clen, wih, ech, bih, bhh, ws);
  k_prepB<<<1537, 256, 0, stream>>>(whh, wlin, ws);
  k_scatter<<<128, 256, 0, stream>>>(clen, ws);
  k_main<<<512, 512, 0, stream>>>(cidx, wemb, blin, outp, ws);
}

// Round 9
// 391.612 us; speedup vs baseline: 3.0761x; 3.0761x over previous
//
#include <hip/hip_runtime.h>

// ============================================================================
// CharLevelEncoder R13b: identical to R13 (container infra failure on first
// submit; code re-audited, no defect). Champion config (R7) + paired-PX
// loads + merged preps. Allocator law learned R5-R12: unified budget =
// 512/waves_per_eu_min; VGPR_Count = arch half. waves_per_eu(2,2) -> 256
// unified (R7, 299us, small overflow); (4,4) -> 128 unified -> wreg[8][8]
// itself spills (R12: VGPR=64, FETCH 2GB, 1136us). 2 blocks/CU unreachable
// with 128 regs of resident W. So: 256 blocks x 512 thr, 8 waves, 1 block/CU.
// R13 deltas vs champion:
//  - PX layout [c][pair][g][hs]: both hs-halves of a lane's gate row adjacent
//    -> ONE dwordx4 (16B) per (r,mt) = 16 loads/thread-step (was 32 x 8B),
//    hoisted per-mt before the MFMA chain so L2 latency drains under MFMA.
//  - preps merged 7 -> 4 launches (R12's merge, verified; ~70us wall).
//  - wemb loads lose NT (4x wave reuse within block).
// ============================================================================

#define NW 32768

typedef __attribute__((ext_vector_type(8))) short short8;
typedef __attribute__((ext_vector_type(4))) float f32x4;
typedef __attribute__((ext_vector_type(4))) int i32x4;
typedef __attribute__((ext_vector_type(8))) unsigned short u16x8;

#define MFMA16(a,b,c) __builtin_amdgcn_mfma_f32_16x16x32_bf16(a,b,c,0,0,0)
#define MFMAI8(a,b,c) __builtin_amdgcn_mfma_i32_16x16x32_i8(a,b,c,0,0,0)

// ---- workspace layout (bytes) ----
#define O_ORDER 0           // i32[32768] sorted word ids (asc len)
#define O_SLEN  131072      // i32[32768] sorted lengths
#define O_WPK   262144      // i8 packed W_hh' fragments (262144)
#define O_USTP  524288      // f32[1024] u' = rowmax(whh)/(127*127)
#define O_WLIN  528384      // bf16 packed W_lin fragments (262144)
#define O_PX    790528      // bf16[256][128][4][2] paired x-proj table (524288)
#define O_BH    1314816     // i32[128][16] per-block length histograms
#define O_BASE  1323008     // i32[128][16] scatter bases
// total 1331200 B

__device__ inline unsigned short f2b(float f) {   // fp32 -> bf16 RNE
  unsigned u = __builtin_bit_cast(unsigned, f);
  u = u + 0x7fffu + ((u >> 16) & 1u);
  return (unsigned short)(u >> 16);
}
__device__ inline float b2f(unsigned short u) {
  return __builtin_bit_cast(float, ((unsigned)u) << 16);
}
__device__ inline float fsigm(float x) {
  float e = __builtin_amdgcn_exp2f(-1.44269504f * x);
  return __builtin_amdgcn_rcpf(1.0f + e);
}
__device__ inline float ftanh(float x) {
  float e = __builtin_amdgcn_exp2f(2.88539008f * x);
  return 1.0f - 2.0f * __builtin_amdgcn_rcpf(e + 1.0f);
}

// ---- prepA: prep0 (row scales) | hist | prep2 (paired PX table) ----
__global__ void k_prepA(const float* __restrict__ whh, const int* __restrict__ lens,
                        const float* __restrict__ wih, const float* __restrict__ ech,
                        const float* __restrict__ bih, const float* __restrict__ bhh,
                        unsigned char* __restrict__ ws) {
  int bid = blockIdx.x, tid = threadIdx.x;
  if (bid < 4) {                        // prep0: per-row scales over W_hh
    int i = bid * 256 + tid;            // 0..1023
    const f32x4* r4 = (const f32x4*)(whh + i * 256);
    float mx = 0.f;
    #pragma unroll 8
    for (int k4 = 0; k4 < 64; ++k4) {
      f32x4 v = r4[k4];
      mx = fmaxf(mx, fmaxf(fmaxf(fabsf(v[0]), fabsf(v[1])),
                           fmaxf(fabsf(v[2]), fabsf(v[3]))));
    }
    ((float*)(ws + O_USTP))[i] = mx / (127.f * 127.f);
    return;
  }
  if (bid < 132) {                      // hist (128 blocks)
    __shared__ int h[16];
    int b2 = bid - 4;
    if (tid < 16) h[tid] = 0;
    __syncthreads();
    int wid = b2 * 256 + tid;
    int l = lens[wid]; l = l < 1 ? 1 : (l > 16 ? 16 : l);
    atomicAdd(&h[l - 1], 1);
    __syncthreads();
    if (tid < 16) ((int*)(ws + O_BH))[b2 * 16 + tid] = h[tid];
    return;
  }
  // prep2: paired PX (1024 blocks). n = g*256 + hd.
  int id = (bid - 132) * 256 + tid;     // 0..262143
  int c = id >> 10, n = id & 1023;
  const f32x4* w4 = (const f32x4*)(wih + n * 64);
  const f32x4* e4 = (const f32x4*)(ech + c * 64);
  float acc = bih[n] + bhh[n];
  #pragma unroll
  for (int k4 = 0; k4 < 16; ++k4) {
    f32x4 a = w4[k4], e = e4[k4];
    acc += a[0] * e[0] + a[1] * e[1] + a[2] * e[2] + a[3] * e[3];
  }
  int g = n >> 8, hd = n & 255;
  int p = ((hd >> 5) << 4) | (hd & 15);   // pair index = w*16 + l15
  int hs = (hd >> 4) & 1;
  ((unsigned short*)(ws + O_PX))[(((c << 7) + p) << 3) + (g << 1) + hs] = f2b(acc);
}

// ---- prepB: scan (block 0) | prep1 pack W_hh' + W_lin (blocks 1..1536) ----
__global__ void k_prepB(const float* __restrict__ whh, const float* __restrict__ wlin,
                        unsigned char* __restrict__ ws) {
  int bid = blockIdx.x, tid = threadIdx.x;
  if (bid == 0) {                       // scan of 128x16 histograms
    __shared__ int tot[16], g[16];
    const int* bh = (const int*)(ws + O_BH);
    int* base = (int*)(ws + O_BASE);
    if (tid < 16) {
      int s = 0;
      for (int b = 0; b < 128; ++b) s += bh[b * 16 + tid];
      tot[tid] = s;
    }
    __syncthreads();
    if (tid == 0) { int a = 0; for (int i = 0; i < 16; ++i) { g[i] = a; a += tot[i]; } }
    __syncthreads();
    if (tid < 16) {
      int run = g[tid];
      for (int b = 0; b < 128; ++b) { base[b * 16 + tid] = run; run += bh[b * 16 + tid]; }
    }
    return;
  }
  int i = (bid - 1) * 256 + tid;        // 0..393215
  if (i < 262144) {                     // W_hh' i8 fragment pack
    int j = i & 7, lane = (i >> 3) & 63, t2 = i >> 9;
    int nt = t2 & 7, u2 = t2 >> 3;
    int kb = u2 & 7, w = u2 >> 3;
    int n = (nt >> 1) * 256 + w * 32 + (nt & 1) * 16 + (lane & 15);
    int k = kb * 32 + (lane >> 4) * 8 + j;
    float v = whh[n * 256 + k];
    float ustep = ((const float*)(ws + O_USTP))[n] * 127.f;   // rowmax/127
    float qf = (ustep > 0.f) ? v / ustep : 0.f;
    int q = (int)__builtin_rintf(qf);
    q = q < -127 ? -127 : (q > 127 ? 127 : q);
    ((signed char*)(ws + O_WPK))[i] = (signed char)q;
    return;
  }
  int i2 = i - 262144;                  // < 131072, W_lin bf16 pack
  {
    int j = i2 & 7, lane = (i2 >> 3) & 63, t3 = i2 >> 9;
    int kf = t3 & 15, nn = t3 >> 4;
    int n = (nn >> 2) * 64 + (nn & 3) * 16 + (lane & 15);
    int k = kf * 32 + (lane >> 4) * 8 + j;
    ((unsigned short*)(ws + O_WLIN))[i2] = f2b(wlin[n * 512 + k]);
  }
}

// ---- scatter (needs BASE) ----
__global__ void k_scatter(const int* __restrict__ lens, unsigned char* __restrict__ ws) {
  __shared__ int cnt[16];
  int t = threadIdx.x, b = blockIdx.x;
  if (t < 16) cnt[t] = 0;
  __syncthreads();
  int wid = b * 256 + t;
  int l = lens[wid]; l = l < 1 ? 1 : (l > 16 ? 16 : l);
  int rank = atomicAdd(&cnt[l - 1], 1);
  int p = ((const int*)(ws + O_BASE))[b * 16 + (l - 1)] + rank;
  ((int*)(ws + O_ORDER))[p] = wid;
  ((int*)(ws + O_SLEN))[p] = l;
}

// ---- main persistent kernel: 256 blocks x 512 threads, 2 waves/SIMD ----
__global__ __launch_bounds__(512)
__attribute__((amdgpu_waves_per_eu(2, 2)))
void k_main(
    const int* __restrict__ cidx, const float* __restrict__ wemb,
    const float* __restrict__ blin, float* __restrict__ outp,
    const unsigned char* __restrict__ ws) {
  // Xb: double-buffered h-state, i8. [buf][mt][kb][lane][8]
  __shared__ signed char Xb[2][4][8][64][8];   // 32 KB
  __shared__ int CW[64][16];                   //  4 KB

  const int tid = threadIdx.x, b = blockIdx.x;
  const int w = tid >> 6, lane = tid & 63;
  const int q = lane >> 4, l15 = lane & 15;
  const int w16l = w * 16 + l15;               // PX pair index

  const int* order = (const int*)(ws + O_ORDER);
  const int* slen  = (const int*)(ws + O_SLEN);
  const signed char* wpk = (const signed char*)(ws + O_WPK);
  const float* upt = (const float*)(ws + O_USTP);
  const unsigned short* wlin = (const unsigned short*)(ws + O_WLIN);
  const unsigned short* pxt = (const unsigned short*)(ws + O_PX);

  // ---- prologue: all of W_hh' -> VGPRs (128 regs), scales ----
  long wreg[8][8];
  #pragma unroll
  for (int kb = 0; kb < 8; ++kb)
    #pragma unroll
    for (int nt = 0; nt < 8; ++nt)
      wreg[kb][nt] = *(const long*)(wpk + (((w * 8 + kb) * 8 + nt) * 64 + lane) * 8);

  float uq[8];
  #pragma unroll
  for (int nt = 0; nt < 8; ++nt) {
    int n = (nt >> 1) * 256 + w * 32 + (nt & 1) * 16 + l15;
    uq[nt] = upt[n];
  }
  const int mh = w >> 2, nw = w & 3;
  float blv[4];
  #pragma unroll
  for (int nt = 0; nt < 4; ++nt) blv[nt] = blin[nw * 64 + nt * 16 + l15];

  // ---- two balanced slices: {b, 511-b} ----
  for (int sl = 0; sl < 2; ++sl) {
    const int s = sl ? (511 - b) : b;
    const int base = 64 * s;
    __syncthreads();                    // prev epilogue's Xb reads done
    { // zero Xb buf0 h-state (16 KB)
      long* pz = (long*)&Xb[0][0][0][0][0];
      #pragma unroll
      for (int ii = 0; ii < 4; ++ii) pz[tid + 512 * ii] = 0L;
    }
    if (tid < 256) {                    // this slice's char indices (streamed once)
      int m = tid >> 2, part = tid & 3;
      int wid = order[base + m];
      *(i32x4*)&CW[m][part * 4] =
          __builtin_nontemporal_load((const i32x4*)(cidx + wid * 16 + part * 4));
    }
    int tmax[4]; unsigned lenpk[4];
    #pragma unroll
    for (int mt = 0; mt < 4; ++mt) {
      int pbm = base + 16 * mt;
      tmax[mt] = slen[pbm + 15];
      unsigned l0 = (unsigned)slen[pbm + q * 4 + 0];
      unsigned l1 = (unsigned)slen[pbm + q * 4 + 1];
      unsigned l2 = (unsigned)slen[pbm + q * 4 + 2];
      unsigned l3 = (unsigned)slen[pbm + q * 4 + 3];
      lenpk[mt] = l0 | (l1 << 8) | (l2 << 16) | (l3 << 24);
    }
    const int Tm = tmax[3];
    __syncthreads();                    // CW + zeroing visible

    float creg[4][2][4];
    unsigned hreg[4][2];
    #pragma unroll
    for (int mt = 0; mt < 4; ++mt)
      #pragma unroll
      for (int hs = 0; hs < 2; ++hs) {
        hreg[mt][hs] = 0u;
        #pragma unroll
        for (int r = 0; r < 4; ++r) creg[mt][hs][r] = 0.f;
      }

    for (int t = 0; t < Tm; ++t) {
      const int rd = t & 1, wb = rd ^ 1;
      #pragma unroll
      for (int mt = 0; mt < 4; ++mt) {
        if (mt != 3 && t >= tmax[mt]) continue;   // wave-uniform
        // ---- issue the 4 paired-PX loads (16B each) up front; they drain
        //      under the MFMA chain below ----
        u16x8 pb8[4];
        #pragma unroll
        for (int r = 0; r < 4; ++r) {
          int cc = CW[mt * 16 + q * 4 + r][t] & 255;
          pb8[r] = *(const u16x8*)&pxt[(((cc << 7) + w16l)) << 3];
        }
        #pragma unroll
        for (int hs = 0; hs < 2; ++hs) {
          i32x4 a0 = (i32x4)0, a1 = (i32x4)0, a2 = (i32x4)0, a3 = (i32x4)0;
          #pragma unroll
          for (int kb = 0; kb < 8; ++kb) {
            long A = *(const long*)&Xb[rd][mt][kb][lane][0];
            a0 = MFMAI8(A, wreg[kb][0 + hs], a0);
            a1 = MFMAI8(A, wreg[kb][2 + hs], a1);
            a2 = MFMAI8(A, wreg[kb][4 + hs], a2);
            a3 = MFMAI8(A, wreg[kb][6 + hs], a3);
          }
          // gates + LSTM update; C-layout row(word) = q*4+r, col(n) = l15
          unsigned hp = 0;
          #pragma unroll
          for (int r = 0; r < 4; ++r) {
            float gi = (float)a0[r] * uq[0 + hs] + b2f(pb8[r][0 + hs]);
            float gf = (float)a1[r] * uq[2 + hs] + b2f(pb8[r][2 + hs]);
            float gg = (float)a2[r] * uq[4 + hs] + b2f(pb8[r][4 + hs]);
            float go = (float)a3[r] * uq[6 + hs] + b2f(pb8[r][6 + hs]);
            float si = fsigm(gi), sf = fsigm(gf);
            float sg = ftanh(gg), so = fsigm(go);
            float cold = creg[mt][hs][r];
            float cn = sf * cold + si * sg;
            float hn = so * ftanh(cn);
            int lene = (int)((lenpk[mt] >> (8 * r)) & 255u);
            bool live = t < lene;
            creg[mt][hs][r] = live ? cn : cold;
            int hq = (int)__builtin_rintf(127.f * hn);   // |hn|<1 -> no clamp
            unsigned ob = (hreg[mt][hs] >> (8 * r)) & 255u;
            unsigned nb = live ? ((unsigned)hq & 255u) : ob;
            hp |= nb << (8 * r);
          }
          hreg[mt][hs] = hp;
        }
      } // mt

      // h write-back into the OTHER buffer (always-write; wave w owns kb = w)
      #pragma unroll
      for (int mt = 0; mt < 4; ++mt) {
        if (mt != 3 && t >= tmax[mt]) continue;
        #pragma unroll
        for (int hs = 0; hs < 2; ++hs) {
          int row16 = 16 * (hs * 2 + (l15 >> 3));
          #pragma unroll
          for (int r = 0; r < 4; ++r)
            Xb[wb][mt][w][(q * 4 + r) + row16][l15 & 7] =
                (signed char)((hreg[mt][hs] >> (8 * r)) & 255u);
        }
      }
      __syncthreads();                  // single barrier per step
    } // t

    // ---- fused final linear for this slice (bf16 MFMA) ----
    int widA[2];
    #pragma unroll
    for (int mi = 0; mi < 2; ++mi) widA[mi] = order[base + (2 * mh + mi) * 16 + l15];
    const int tb0 = (mh ? tmax[2] : tmax[0]) & 1;   // buffer holding final h
    const int tb1 = (mh ? tmax[3] : tmax[1]) & 1;
    f32x4 fac[2][4];
    #pragma unroll
    for (int mi = 0; mi < 2; ++mi)
      #pragma unroll
      for (int nt = 0; nt < 4; ++nt) fac[mi][nt] = 0.0f;

    #pragma unroll
    for (int kf = 0; kf < 16; ++kf) {
      short8 Bn[4];
      #pragma unroll
      for (int nt = 0; nt < 4; ++nt)
        Bn[nt] = ((const short8*)wlin)[((nw * 4 + nt) * 16 + kf) * 64 + lane];
      short8 Am[2];
      #pragma unroll
      for (int mi = 0; mi < 2; ++mi) {
        if (kf < 8) {                   // word_emb fp32 -> bf16 (L2 reuse: no NT)
          const f32x4* pa = (const f32x4*)(wemb + widA[mi] * 256 + kf * 32 + q * 8);
          f32x4 f0 = pa[0];
          f32x4 f1 = pa[1];
          short8 A;
          A[0] = (short)f2b(f0[0]); A[1] = (short)f2b(f0[1]);
          A[2] = (short)f2b(f0[2]); A[3] = (short)f2b(f0[3]);
          A[4] = (short)f2b(f1[0]); A[5] = (short)f2b(f1[1]);
          A[6] = (short)f2b(f1[2]); A[7] = (short)f2b(f1[3]);
          Am[mi] = A;
        } else {                        // final h from Xb i8 -> bf16
          int mtv = 2 * mh + mi;
          int tb = mi ? tb1 : tb0;
          long ch = *(const long*)&Xb[tb][mtv][kf - 8][lane][0];
          short8 A;
          #pragma unroll
          for (int j = 0; j < 8; ++j) {
            int v = (int)(signed char)((ch >> (8 * j)) & 255);
            A[j] = (short)f2b((float)v * (1.f / 127.f));
          }
          Am[mi] = A;
        }
      }
      #pragma unroll
      for (int mi = 0; mi < 2; ++mi)
        #pragma unroll
        for (int nt = 0; nt < 4; ++nt)
          fac[mi][nt] = MFMA16(Am[mi], Bn[nt], fac[mi][nt]);
    }
    #pragma unroll
    for (int mi = 0; mi < 2; ++mi) {
      #pragma unroll
      for (int r = 0; r < 4; ++r) {
        int wid = order[base + (2 * mh + mi) * 16 + q * 4 + r];
        float* po = outp + wid * 256 + nw * 64 + l15;
        #pragma unroll
        for (int nt = 0; nt < 4; ++nt) {
          float v = fac[mi][nt][r] + blv[nt];
          __builtin_nontemporal_store(v > 0.f ? v : 0.f, po + nt * 16);
        }
      }
    }
  } // slice
}

extern "C" void kernel_launch(void* const* d_in, const int* in_sizes, int n_in,
                              void* d_out, int out_size, void* d_ws, size_t ws_size,
                              hipStream_t stream) {
  const int*   cidx = (const int*)d_in[0];
  const int*   clen = (const int*)d_in[1];
  const float* wemb = (const float*)d_in[2];
  const float* ech  = (const float*)d_in[3];
  const float* wih  = (const float*)d_in[4];
  const float* whh  = (const float*)d_in[5];
  const float* bih  = (const float*)d_in[6];
  const float* bhh  = (const float*)d_in[7];
  const float* wlin = (const float*)d_in[8];
  const float* blin = (const float*)d_in[9];
  float* outp = (float*)d_out;
  unsigned char* ws = (unsigned char*)d_ws;

  k_prepA<<<1156, 256, 0, stream>>>(whh, clen, wih, ech, bih, bhh, ws);
  k_prepB<<<1537, 256, 0, stream>>>(whh, wlin, ws);
  k_scatter<<<128, 256, 0, stream>>>(clen, ws);
  k_main<<<256, 512, 0, stream>>>(cidx, wemb, blin, outp, ws);
}

// Round 10
// 371.587 us; speedup vs baseline: 3.2419x; 1.0539x over previous
//
#include <hip/hip_runtime.h>

// ============================================================================
// CharLevelEncoder R14: native-K i8 MFMA (16x16x64) -- halve MFMA+LDS issue.
// R13b post-mortem: PX pairing <5% -> gather latency off critical path.
// Mystery FETCH/WRITE excess reinterpreted: PX-gather L2 misses + clean
// victim writebacks into L3 (TCC counts L2<->L3) -- benign, stop chasing.
// Counters say work-dominated: MfmaUtil 21.5% (~8.7k cyc/SIMD/step) +
// VALUBusy 43% (~17k) = ~65% of the 40k step. Cut instructions:
//  - mfma_i32_16x16x64_i8 (native gfx950 shape, 2x rate): 128 MFMA/wave-step
//    (was 256), 8 ds_read_b128/mt (was 16 b64). Same 128 VGPRs of W
//    (4 kb2 x 8 frag x 4 regs). Layout: lane l -> {m=l&15, k=kb2*64+
//    (l>>4)*16+j} (gfx950 K/4-contiguous pattern, m89-verified family).
//  - liveness test hoisted out of hs loop (was computed 2x).
// Everything else = R13b champion (256 x 512thr, waves_per_eu(2,2),
// paired PX, merged preps, double-buffered Xb, 1 barrier/step).
// ============================================================================

#define NW 32768

typedef __attribute__((ext_vector_type(8))) short short8;
typedef __attribute__((ext_vector_type(4))) float f32x4;
typedef __attribute__((ext_vector_type(4))) int i32x4;
typedef __attribute__((ext_vector_type(8))) unsigned short u16x8;

#define MFMA16(a,b,c) __builtin_amdgcn_mfma_f32_16x16x32_bf16(a,b,c,0,0,0)
#define MFMAI8(a,b,c) __builtin_amdgcn_mfma_i32_16x16x64_i8(a,b,c,0,0,0)

// ---- workspace layout (bytes) ----
#define O_ORDER 0           // i32[32768] sorted word ids (asc len)
#define O_SLEN  131072      // i32[32768] sorted lengths
#define O_WPK   262144      // i8 packed W_hh' fragments, K=64 shape (262144)
#define O_USTP  524288      // f32[1024] u' = rowmax(whh)/(127*127)
#define O_WLIN  528384      // bf16 packed W_lin fragments (262144)
#define O_PX    790528      // bf16[256][128][4][2] paired x-proj table (524288)
#define O_BH    1314816     // i32[128][16] per-block length histograms
#define O_BASE  1323008     // i32[128][16] scatter bases
// total 1331200 B

__device__ inline unsigned short f2b(float f) {   // fp32 -> bf16 RNE
  unsigned u = __builtin_bit_cast(unsigned, f);
  u = u + 0x7fffu + ((u >> 16) & 1u);
  return (unsigned short)(u >> 16);
}
__device__ inline float b2f(unsigned short u) {
  return __builtin_bit_cast(float, ((unsigned)u) << 16);
}
__device__ inline float fsigm(float x) {
  float e = __builtin_amdgcn_exp2f(-1.44269504f * x);
  return __builtin_amdgcn_rcpf(1.0f + e);
}
__device__ inline float ftanh(float x) {
  float e = __builtin_amdgcn_exp2f(2.88539008f * x);
  return 1.0f - 2.0f * __builtin_amdgcn_rcpf(e + 1.0f);
}

// ---- prepA: prep0 (row scales) | hist | prep2 (paired PX table) ----
__global__ void k_prepA(const float* __restrict__ whh, const int* __restrict__ lens,
                        const float* __restrict__ wih, const float* __restrict__ ech,
                        const float* __restrict__ bih, const float* __restrict__ bhh,
                        unsigned char* __restrict__ ws) {
  int bid = blockIdx.x, tid = threadIdx.x;
  if (bid < 4) {                        // prep0: per-row scales over W_hh
    int i = bid * 256 + tid;            // 0..1023
    const f32x4* r4 = (const f32x4*)(whh + i * 256);
    float mx = 0.f;
    #pragma unroll 8
    for (int k4 = 0; k4 < 64; ++k4) {
      f32x4 v = r4[k4];
      mx = fmaxf(mx, fmaxf(fmaxf(fabsf(v[0]), fabsf(v[1])),
                           fmaxf(fabsf(v[2]), fabsf(v[3]))));
    }
    ((float*)(ws + O_USTP))[i] = mx / (127.f * 127.f);
    return;
  }
  if (bid < 132) {                      // hist (128 blocks)
    __shared__ int h[16];
    int b2 = bid - 4;
    if (tid < 16) h[tid] = 0;
    __syncthreads();
    int wid = b2 * 256 + tid;
    int l = lens[wid]; l = l < 1 ? 1 : (l > 16 ? 16 : l);
    atomicAdd(&h[l - 1], 1);
    __syncthreads();
    if (tid < 16) ((int*)(ws + O_BH))[b2 * 16 + tid] = h[tid];
    return;
  }
  // prep2: paired PX (1024 blocks). n = g*256 + hd.
  int id = (bid - 132) * 256 + tid;     // 0..262143
  int c = id >> 10, n = id & 1023;
  const f32x4* w4 = (const f32x4*)(wih + n * 64);
  const f32x4* e4 = (const f32x4*)(ech + c * 64);
  float acc = bih[n] + bhh[n];
  #pragma unroll
  for (int k4 = 0; k4 < 16; ++k4) {
    f32x4 a = w4[k4], e = e4[k4];
    acc += a[0] * e[0] + a[1] * e[1] + a[2] * e[2] + a[3] * e[3];
  }
  int g = n >> 8, hd = n & 255;
  int p = ((hd >> 5) << 4) | (hd & 15);   // pair index = w*16 + l15
  int hs = (hd >> 4) & 1;
  ((unsigned short*)(ws + O_PX))[(((c << 7) + p) << 3) + (g << 1) + hs] = f2b(acc);
}

// ---- prepB: scan (block 0) | prep1 pack W_hh' (K=64 frags) + W_lin ----
__global__ void k_prepB(const float* __restrict__ whh, const float* __restrict__ wlin,
                        unsigned char* __restrict__ ws) {
  int bid = blockIdx.x, tid = threadIdx.x;
  if (bid == 0) {                       // scan of 128x16 histograms
    __shared__ int tot[16], g[16];
    const int* bh = (const int*)(ws + O_BH);
    int* base = (int*)(ws + O_BASE);
    if (tid < 16) {
      int s = 0;
      for (int b = 0; b < 128; ++b) s += bh[b * 16 + tid];
      tot[tid] = s;
    }
    __syncthreads();
    if (tid == 0) { int a = 0; for (int i = 0; i < 16; ++i) { g[i] = a; a += tot[i]; } }
    __syncthreads();
    if (tid < 16) {
      int run = g[tid];
      for (int b = 0; b < 128; ++b) { base[b * 16 + tid] = run; run += bh[b * 16 + tid]; }
    }
    return;
  }
  int i = (bid - 1) * 256 + tid;        // 0..393215
  if (i < 262144) {                     // W_hh' i8 K=64 fragment pack
    // flat: (((w*4+kb2)*8+nt)*64+lane)*16 + j
    int j = i & 15, lane = (i >> 4) & 63, t2 = i >> 10;
    int nt = t2 & 7, u2 = t2 >> 3;
    int kb2 = u2 & 3, w = u2 >> 2;
    int n = (nt >> 1) * 256 + w * 32 + (nt & 1) * 16 + (lane & 15);
    int k = kb2 * 64 + (lane >> 4) * 16 + j;
    float v = whh[n * 256 + k];
    float ustep = ((const float*)(ws + O_USTP))[n] * 127.f;   // rowmax/127
    float qf = (ustep > 0.f) ? v / ustep : 0.f;
    int q = (int)__builtin_rintf(qf);
    q = q < -127 ? -127 : (q > 127 ? 127 : q);
    ((signed char*)(ws + O_WPK))[i] = (signed char)q;
    return;
  }
  int i2 = i - 262144;                  // < 131072, W_lin bf16 pack
  {
    int j = i2 & 7, lane = (i2 >> 3) & 63, t3 = i2 >> 9;
    int kf = t3 & 15, nn = t3 >> 4;
    int n = (nn >> 2) * 64 + (nn & 3) * 16 + (lane & 15);
    int k = kf * 32 + (lane >> 4) * 8 + j;
    ((unsigned short*)(ws + O_WLIN))[i2] = f2b(wlin[n * 512 + k]);
  }
}

// ---- scatter (needs BASE) ----
__global__ void k_scatter(const int* __restrict__ lens, unsigned char* __restrict__ ws) {
  __shared__ int cnt[16];
  int t = threadIdx.x, b = blockIdx.x;
  if (t < 16) cnt[t] = 0;
  __syncthreads();
  int wid = b * 256 + t;
  int l = lens[wid]; l = l < 1 ? 1 : (l > 16 ? 16 : l);
  int rank = atomicAdd(&cnt[l - 1], 1);
  int p = ((const int*)(ws + O_BASE))[b * 16 + (l - 1)] + rank;
  ((int*)(ws + O_ORDER))[p] = wid;
  ((int*)(ws + O_SLEN))[p] = l;
}

// ---- main persistent kernel: 256 blocks x 512 threads, 2 waves/SIMD ----
__global__ __launch_bounds__(512)
__attribute__((amdgpu_waves_per_eu(2, 2)))
void k_main(
    const int* __restrict__ cidx, const float* __restrict__ wemb,
    const float* __restrict__ blin, float* __restrict__ outp,
    const unsigned char* __restrict__ ws) {
  // Xb: double-buffered h-state, i8, K=64 A-frag layout. [buf][mt][kb2][lane][16]
  __shared__ signed char Xb[2][4][4][64][16];  // 32 KB
  __shared__ int CW[64][16];                   //  4 KB

  const int tid = threadIdx.x, b = blockIdx.x;
  const int w = tid >> 6, lane = tid & 63;
  const int q = lane >> 4, l15 = lane & 15;
  const int w16l = w * 16 + l15;               // PX pair index
  const int kb2w = w >> 1;                     // h write-back kb2

  const int* order = (const int*)(ws + O_ORDER);
  const int* slen  = (const int*)(ws + O_SLEN);
  const signed char* wpk = (const signed char*)(ws + O_WPK);
  const float* upt = (const float*)(ws + O_USTP);
  const unsigned short* wlin = (const unsigned short*)(ws + O_WLIN);
  const unsigned short* pxt = (const unsigned short*)(ws + O_PX);

  // ---- prologue: all of W_hh' -> VGPRs (128 regs: 4 kb2 x 8 frag x 4) ----
  i32x4 wreg[4][8];
  #pragma unroll
  for (int kb2 = 0; kb2 < 4; ++kb2)
    #pragma unroll
    for (int nt = 0; nt < 8; ++nt)
      wreg[kb2][nt] = *(const i32x4*)(wpk + (((w * 4 + kb2) * 8 + nt) * 64 + lane) * 16);

  float uq[8];
  #pragma unroll
  for (int nt = 0; nt < 8; ++nt) {
    int n = (nt >> 1) * 256 + w * 32 + (nt & 1) * 16 + l15;
    uq[nt] = upt[n];
  }
  const int mh = w >> 2, nw = w & 3;
  float blv[4];
  #pragma unroll
  for (int nt = 0; nt < 4; ++nt) blv[nt] = blin[nw * 64 + nt * 16 + l15];

  // ---- two balanced slices: {b, 511-b} ----
  for (int sl = 0; sl < 2; ++sl) {
    const int s = sl ? (511 - b) : b;
    const int base = 64 * s;
    __syncthreads();                    // prev epilogue's Xb reads done
    { // zero Xb buf0 h-state (16 KB)
      long* pz = (long*)&Xb[0][0][0][0][0];
      #pragma unroll
      for (int ii = 0; ii < 4; ++ii) pz[tid + 512 * ii] = 0L;
    }
    if (tid < 256) {                    // this slice's char indices (streamed once)
      int m = tid >> 2, part = tid & 3;
      int wid = order[base + m];
      *(i32x4*)&CW[m][part * 4] =
          __builtin_nontemporal_load((const i32x4*)(cidx + wid * 16 + part * 4));
    }
    int tmax[4]; unsigned lenpk[4];
    #pragma unroll
    for (int mt = 0; mt < 4; ++mt) {
      int pbm = base + 16 * mt;
      tmax[mt] = slen[pbm + 15];
      unsigned l0 = (unsigned)slen[pbm + q * 4 + 0];
      unsigned l1 = (unsigned)slen[pbm + q * 4 + 1];
      unsigned l2 = (unsigned)slen[pbm + q * 4 + 2];
      unsigned l3 = (unsigned)slen[pbm + q * 4 + 3];
      lenpk[mt] = l0 | (l1 << 8) | (l2 << 16) | (l3 << 24);
    }
    const int Tm = tmax[3];
    __syncthreads();                    // CW + zeroing visible

    float creg[4][2][4];
    unsigned hreg[4][2];
    #pragma unroll
    for (int mt = 0; mt < 4; ++mt)
      #pragma unroll
      for (int hs = 0; hs < 2; ++hs) {
        hreg[mt][hs] = 0u;
        #pragma unroll
        for (int r = 0; r < 4; ++r) creg[mt][hs][r] = 0.f;
      }

    for (int t = 0; t < Tm; ++t) {
      const int rd = t & 1, wb = rd ^ 1;
      #pragma unroll
      for (int mt = 0; mt < 4; ++mt) {
        if (mt != 3 && t >= tmax[mt]) continue;   // wave-uniform
        // paired-PX loads (16B each) up front; drain under the MFMA chain
        u16x8 pb8[4];
        #pragma unroll
        for (int r = 0; r < 4; ++r) {
          int cc = CW[mt * 16 + q * 4 + r][t] & 255;
          pb8[r] = *(const u16x8*)&pxt[(((cc << 7) + w16l)) << 3];
        }
        bool lv[4];                     // liveness, hoisted (shared by both hs)
        #pragma unroll
        for (int r = 0; r < 4; ++r)
          lv[r] = t < (int)((lenpk[mt] >> (8 * r)) & 255u);
        #pragma unroll
        for (int hs = 0; hs < 2; ++hs) {
          i32x4 a0 = (i32x4)0, a1 = (i32x4)0, a2 = (i32x4)0, a3 = (i32x4)0;
          #pragma unroll
          for (int kb2 = 0; kb2 < 4; ++kb2) {
            i32x4 A = *(const i32x4*)&Xb[rd][mt][kb2][lane][0];
            a0 = MFMAI8(A, wreg[kb2][0 + hs], a0);
            a1 = MFMAI8(A, wreg[kb2][2 + hs], a1);
            a2 = MFMAI8(A, wreg[kb2][4 + hs], a2);
            a3 = MFMAI8(A, wreg[kb2][6 + hs], a3);
          }
          // gates + LSTM update; C-layout row(word) = q*4+r, col(n) = l15
          unsigned hp = 0;
          #pragma unroll
          for (int r = 0; r < 4; ++r) {
            float gi = (float)a0[r] * uq[0 + hs] + b2f(pb8[r][0 + hs]);
            float gf = (float)a1[r] * uq[2 + hs] + b2f(pb8[r][2 + hs]);
            float gg = (float)a2[r] * uq[4 + hs] + b2f(pb8[r][4 + hs]);
            float go = (float)a3[r] * uq[6 + hs] + b2f(pb8[r][6 + hs]);
            float si = fsigm(gi), sf = fsigm(gf);
            float sg = ftanh(gg), so = fsigm(go);
            float cold = creg[mt][hs][r];
            float cn = sf * cold + si * sg;
            float hn = so * ftanh(cn);
            creg[mt][hs][r] = lv[r] ? cn : cold;
            int hq = (int)__builtin_rintf(127.f * hn);   // |hn|<1 -> no clamp
            unsigned ob = (hreg[mt][hs] >> (8 * r)) & 255u;
            unsigned nb = lv[r] ? ((unsigned)hq & 255u) : ob;
            hp |= nb << (8 * r);
          }
          hreg[mt][hs] = hp;
        }
      } // mt

      // h write-back into the OTHER buffer.
      // n = w*32 + hs*16 + l15 -> kb2' = w>>1, lanepart = (w&1)*2+hs, j = l15.
      #pragma unroll
      for (int mt = 0; mt < 4; ++mt) {
        if (mt != 3 && t >= tmax[mt]) continue;
        #pragma unroll
        for (int hs = 0; hs < 2; ++hs) {
          int row16 = 16 * ((w & 1) * 2 + hs);
          #pragma unroll
          for (int r = 0; r < 4; ++r)
            Xb[wb][mt][kb2w][(q * 4 + r) + row16][l15] =
                (signed char)((hreg[mt][hs] >> (8 * r)) & 255u);
        }
      }
      __syncthreads();                  // single barrier per step
    } // t

    // ---- fused final linear for this slice (bf16 MFMA) ----
    int widA[2];
    #pragma unroll
    for (int mi = 0; mi < 2; ++mi) widA[mi] = order[base + (2 * mh + mi) * 16 + l15];
    const int tb0 = (mh ? tmax[2] : tmax[0]) & 1;   // buffer holding final h
    const int tb1 = (mh ? tmax[3] : tmax[1]) & 1;
    f32x4 fac[2][4];
    #pragma unroll
    for (int mi = 0; mi < 2; ++mi)
      #pragma unroll
      for (int nt = 0; nt < 4; ++nt) fac[mi][nt] = 0.0f;

    #pragma unroll
    for (int kf = 0; kf < 16; ++kf) {
      short8 Bn[4];
      #pragma unroll
      for (int nt = 0; nt < 4; ++nt)
        Bn[nt] = ((const short8*)wlin)[((nw * 4 + nt) * 16 + kf) * 64 + lane];
      short8 Am[2];
      #pragma unroll
      for (int mi = 0; mi < 2; ++mi) {
        if (kf < 8) {                   // word_emb fp32 -> bf16 (L2 reuse: no NT)
          const f32x4* pa = (const f32x4*)(wemb + widA[mi] * 256 + kf * 32 + q * 8);
          f32x4 f0 = pa[0];
          f32x4 f1 = pa[1];
          short8 A;
          A[0] = (short)f2b(f0[0]); A[1] = (short)f2b(f0[1]);
          A[2] = (short)f2b(f0[2]); A[3] = (short)f2b(f0[3]);
          A[4] = (short)f2b(f1[0]); A[5] = (short)f2b(f1[1]);
          A[6] = (short)f2b(f1[2]); A[7] = (short)f2b(f1[3]);
          Am[mi] = A;
        } else {                        // final h from Xb (K=64 layout) -> bf16
          int mtv = 2 * mh + mi;
          int tb = mi ? tb1 : tb0;
          int hkb = (kf - 8) * 32 + q * 8;      // base h-dim of this lane's 8
          int kb2 = hkb >> 6, off = hkb & 63;
          long ch = *(const long*)&Xb[tb][mtv][kb2][l15 + 16 * (off >> 4)][off & 8];
          short8 A;
          #pragma unroll
          for (int j = 0; j < 8; ++j) {
            int v = (int)(signed char)((ch >> (8 * j)) & 255);
            A[j] = (short)f2b((float)v * (1.f / 127.f));
          }
          Am[mi] = A;
        }
      }
      #pragma unroll
      for (int mi = 0; mi < 2; ++mi)
        #pragma unroll
        for (int nt = 0; nt < 4; ++nt)
          fac[mi][nt] = MFMA16(Am[mi], Bn[nt], fac[mi][nt]);
    }
    #pragma unroll
    for (int mi = 0; mi < 2; ++mi) {
      #pragma unroll
      for (int r = 0; r < 4; ++r) {
        int wid = order[base + (2 * mh + mi) * 16 + q * 4 + r];
        float* po = outp + wid * 256 + nw * 64 + l15;
        #pragma unroll
        for (int nt = 0; nt < 4; ++nt) {
          float v = fac[mi][nt][r] + blv[nt];
          __builtin_nontemporal_store(v > 0.f ? v : 0.f, po + nt * 16);
        }
      }
    }
  } // slice
}

extern "C" void kernel_launch(void* const* d_in, const int* in_sizes, int n_in,
                              void* d_out, int out_size, void* d_ws, size_t ws_size,
                              hipStream_t stream) {
  const int*   cidx = (const int*)d_in[0];
  const int*   clen = (const int*)d_in[1];
  const float* wemb = (const float*)d_in[2];
  const float* ech  = (const float*)d_in[3];
  const float* wih  = (const float*)d_in[4];
  const float* whh  = (const float*)d_in[5];
  const float* bih  = (const float*)d_in[6];
  const float* bhh  = (const float*)d_in[7];
  const float* wlin = (const float*)d_in[8];
  const float* blin = (const float*)d_in[9];
  float* outp = (float*)d_out;
  unsigned char* ws = (unsigned char*)d_ws;

  k_prepA<<<1156, 256, 0, stream>>>(whh, clen, wih, ech, bih, bhh, ws);
  k_prepB<<<1537, 256, 0, stream>>>(whh, wlin, ws);
  k_scatter<<<128, 256, 0, stream>>>(clen, ws);
  k_main<<<256, 512, 0, stream>>>(cidx, wemb, blin, outp, ws);
}